// Round 1
// baseline (395.670 us; speedup 1.0000x reference)
//
#include <hip/hip_runtime.h>

#define LSEQ 768
#define CIN 384
#define DOUT 32
#define EOUT 128
#define EPS 1e-5f
#define JT 96

// ---------------- Phase 1: LayerNorm + left/right projections + L2/R2 tables ----------------
__global__ __launch_bounds__(384) void k_ln_proj(
    const float* __restrict__ act, const float* __restrict__ mask,
    const float* __restrict__ nw, const float* __restrict__ nb,
    const float* __restrict__ wl, const float* __restrict__ bl,
    const float* __restrict__ wr, const float* __restrict__ br,
    const float* __restrict__ wo,
    float* __restrict__ left, float* __restrict__ right,
    float* __restrict__ l2, float* __restrict__ r2)
{
    const int row = blockIdx.x;
    const int t = threadIdx.x;
    __shared__ float red[6];
    __shared__ float norm_s[CIN];
    __shared__ float part[64][6];
    __shared__ float lr_s[64];

    float a = act[row * CIN + t];

    // mean
    float v = a;
    #pragma unroll
    for (int off = 32; off; off >>= 1) v += __shfl_down(v, off, 64);
    const int wave = t >> 6;
    if ((t & 63) == 0) red[wave] = v;
    __syncthreads();
    float mu = (red[0] + red[1] + red[2] + red[3] + red[4] + red[5]) * (1.0f / CIN);

    // variance
    float d = a - mu;
    v = d * d;
    #pragma unroll
    for (int off = 32; off; off >>= 1) v += __shfl_down(v, off, 64);
    __syncthreads();
    if ((t & 63) == 0) red[wave] = v;
    __syncthreads();
    float var = (red[0] + red[1] + red[2] + red[3] + red[4] + red[5]) * (1.0f / CIN);
    float rstd = rsqrtf(var + EPS);

    norm_s[t] = d * rstd * nw[t] + nb[t];
    __syncthreads();

    // left/right projections: 64 outputs x 6 chunks of 64 channels
    const int dd = t & 63;          // output index (0..31 left, 32..63 right)
    const int chunk = t >> 6;       // 0..5
    const float* __restrict__ w = (dd < DOUT) ? wl : wr;
    const int dcol = dd & (DOUT - 1);
    const int c0 = chunk * 64;
    float p = 0.f;
    #pragma unroll 8
    for (int c = 0; c < 64; ++c)
        p = fmaf(norm_s[c0 + c], w[(c0 + c) * DOUT + dcol], p);
    part[dd][chunk] = p;
    __syncthreads();

    if (t < 64) {
        float s = part[t][0] + part[t][1] + part[t][2] + part[t][3] + part[t][4] + part[t][5];
        float bias = (t < DOUT) ? bl[t] : br[t - DOUT];
        float val = (s + bias) * mask[row];
        lr_s[t] = val;
        if (t < DOUT) left[row * DOUT + t] = val;
        else          right[row * DOUT + (t - DOUT)] = val;
    }
    __syncthreads();

    // L2[row,e] = sum_d left[row,d]*wo2[d,e];  R2 likewise (wo2 = rows 32..63 of wo)
    if (t < 256) {
        const int e = t & (EOUT - 1);
        const bool isR = (t >= EOUT);
        const float* __restrict__ lr = isR ? (lr_s + DOUT) : lr_s;
        float acc = 0.f;
        #pragma unroll
        for (int dq = 0; dq < DOUT; ++dq)
            acc = fmaf(lr[dq], wo[(DOUT + dq) * EOUT + e], acc);
        (isR ? r2 : l2)[row * EOUT + e] = acc;
    }
}

// ---------------- Phase 2: out[i,j,e] = sum_d left[j,d]*right[i,d]*wo1[d,e] + L2[j,e] - R2[i,e] + bo[e]
__global__ __launch_bounds__(128) void k_outer(
    const float* __restrict__ left, const float* __restrict__ right,
    const float* __restrict__ l2, const float* __restrict__ r2,
    const float* __restrict__ wo, const float* __restrict__ bo,
    float* __restrict__ out)
{
    const int i = blockIdx.x;
    const int j0 = blockIdx.y * JT;
    const int e = threadIdx.x;

    // per-thread weights: wi[d] = right[i,d] * wo1[d,e]  (32 VGPRs)
    const float* __restrict__ Rrow = right + i * DOUT;   // uniform address -> s_load
    float wi[DOUT];
    #pragma unroll
    for (int d = 0; d < DOUT; ++d)
        wi[d] = Rrow[d] * wo[d * EOUT + e];

    const float base = bo[e] - r2[i * EOUT + e];
    const float* __restrict__ l2p = l2 + (size_t)j0 * EOUT + e;
    float* __restrict__ op = out + ((size_t)i * LSEQ + j0) * EOUT + e;

    #pragma unroll 2
    for (int j = 0; j < JT; ++j) {
        const float* __restrict__ Lrow = left + (size_t)(j0 + j) * DOUT; // uniform -> s_load
        float acc = base;
        #pragma unroll
        for (int d = 0; d < DOUT; ++d)
            acc = fmaf(Lrow[d], wi[d], acc);
        acc += l2p[(size_t)j * EOUT];
        op[(size_t)j * EOUT] = acc;
    }
}

extern "C" void kernel_launch(void* const* d_in, const int* in_sizes, int n_in,
                              void* d_out, int out_size, void* d_ws, size_t ws_size,
                              hipStream_t stream) {
    const float* act  = (const float*)d_in[0];
    const float* mask = (const float*)d_in[1];
    const float* nw   = (const float*)d_in[2];
    const float* nb   = (const float*)d_in[3];
    const float* wl   = (const float*)d_in[4];
    const float* bl   = (const float*)d_in[5];
    const float* wr   = (const float*)d_in[6];
    const float* br   = (const float*)d_in[7];
    const float* wo   = (const float*)d_in[8];
    const float* bo   = (const float*)d_in[9];
    float* out = (float*)d_out;

    float* ws    = (float*)d_ws;
    float* left  = ws;                      // 768*32
    float* right = ws + LSEQ * DOUT;        // 768*32
    float* l2    = ws + 2 * LSEQ * DOUT;    // 768*128
    float* r2    = l2 + LSEQ * EOUT;        // 768*128

    hipLaunchKernelGGL(k_ln_proj, dim3(LSEQ), dim3(384), 0, stream,
                       act, mask, nw, nb, wl, bl, wr, br, wo,
                       left, right, l2, r2);
    hipLaunchKernelGGL(k_outer, dim3(LSEQ, LSEQ / JT), dim3(128), 0, stream,
                       left, right, l2, r2, wo, bo, out);
}

// Round 2
// 363.507 us; speedup vs baseline: 1.0885x; 1.0885x over previous
//
#include <hip/hip_runtime.h>
#include <hip/hip_bf16.h>

#define LSEQ 768
#define CIN 384
#define DOUT 32
#define EOUT 128
#define EPS 1e-5f

typedef __attribute__((ext_vector_type(8))) short bf16x8;
typedef __attribute__((ext_vector_type(4))) float f32x4;

// ---------------- Phase 1: LayerNorm + left/right projections + L2/R2 tables ----------------
__global__ __launch_bounds__(384) void k_ln_proj(
    const float* __restrict__ act, const float* __restrict__ mask,
    const float* __restrict__ nw, const float* __restrict__ nb,
    const float* __restrict__ wl, const float* __restrict__ bl,
    const float* __restrict__ wr, const float* __restrict__ br,
    const float* __restrict__ wo,
    __hip_bfloat16* __restrict__ left_bf, float* __restrict__ right,
    float* __restrict__ l2, float* __restrict__ r2)
{
    const int row = blockIdx.x;
    const int t = threadIdx.x;
    __shared__ float red[6];
    __shared__ float norm_s[CIN];
    __shared__ float part[64][6];
    __shared__ float lr_s[64];

    float a = act[row * CIN + t];

    // mean
    float v = a;
    #pragma unroll
    for (int off = 32; off; off >>= 1) v += __shfl_down(v, off, 64);
    const int wave = t >> 6;
    if ((t & 63) == 0) red[wave] = v;
    __syncthreads();
    float mu = (red[0] + red[1] + red[2] + red[3] + red[4] + red[5]) * (1.0f / CIN);

    // variance
    float d = a - mu;
    v = d * d;
    #pragma unroll
    for (int off = 32; off; off >>= 1) v += __shfl_down(v, off, 64);
    __syncthreads();
    if ((t & 63) == 0) red[wave] = v;
    __syncthreads();
    float var = (red[0] + red[1] + red[2] + red[3] + red[4] + red[5]) * (1.0f / CIN);
    float rstd = rsqrtf(var + EPS);

    norm_s[t] = d * rstd * nw[t] + nb[t];
    __syncthreads();

    // left/right projections: 64 outputs x 6 chunks of 64 channels
    const int dd = t & 63;          // output index (0..31 left, 32..63 right)
    const int chunk = t >> 6;       // 0..5
    const float* __restrict__ w = (dd < DOUT) ? wl : wr;
    const int dcol = dd & (DOUT - 1);
    const int c0 = chunk * 64;
    float p = 0.f;
    #pragma unroll 8
    for (int c = 0; c < 64; ++c)
        p = fmaf(norm_s[c0 + c], w[(c0 + c) * DOUT + dcol], p);
    part[dd][chunk] = p;
    __syncthreads();

    if (t < 64) {
        float s = part[t][0] + part[t][1] + part[t][2] + part[t][3] + part[t][4] + part[t][5];
        float bias = (t < DOUT) ? bl[t] : br[t - DOUT];
        float val = (s + bias) * mask[row];
        lr_s[t] = val;
        if (t < DOUT) left_bf[row * DOUT + t] = __float2bfloat16(val);
        else          right[row * DOUT + (t - DOUT)] = val;
    }
    __syncthreads();

    // L2[row,e] = sum_d left[row,d]*wo2[d,e];  R2 likewise (wo2 = rows 32..63 of wo)
    if (t < 256) {
        const int e = t & (EOUT - 1);
        const bool isR = (t >= EOUT);
        const float* __restrict__ lr = isR ? (lr_s + DOUT) : lr_s;
        float acc = 0.f;
        #pragma unroll
        for (int dq = 0; dq < DOUT; ++dq)
            acc = fmaf(lr[dq], wo[(DOUT + dq) * EOUT + e], acc);
        (isR ? r2 : l2)[row * EOUT + e] = acc;
    }
}

// ---------------- Phase 2: out[i,j,e] = MFMA bilinear + l2[j,e] - r2[i,e] + bo[e] ----------
// One block per i. 8 waves; wave w owns e-tile [16w, 16w+16).
// B-frag (per lane): Wg[k][e] = right[i,k]*wo1[k,e], k = 8g+q (g = lane>>4, q = 0..7).
// A-frag (per lane): left_bf[j-tile row (lane&15)][k = 8g+q] -> 16B contiguous load.
// k-mapping is self-canceling (same bijection on A and B); C/D map is the m89-verified
// col = lane&15, row = 4*(lane>>4) + reg.
__global__ __launch_bounds__(512) void k_outer_mfma(
    const __hip_bfloat16* __restrict__ left_bf,
    const float* __restrict__ right,
    const float* __restrict__ l2, const float* __restrict__ r2,
    const float* __restrict__ wo, const float* __restrict__ bo,
    float* __restrict__ out)
{
    const int i = blockIdx.x;
    const int t = threadIdx.x;
    const int lane = t & 63;
    const int wv = t >> 6;          // 0..7 -> e-tile
    const int n = lane & 15;
    const int g = lane >> 4;        // 0..3
    const int e = wv * 16 + n;

    // Build B fragment in registers
    bf16x8 bfrag;
    const float* __restrict__ Rrow = right + i * DOUT;
    #pragma unroll
    for (int q = 0; q < 8; ++q) {
        const int k = 8 * g + q;
        const float v = Rrow[k] * wo[k * EOUT + e];
        __hip_bfloat16 h = __float2bfloat16(v);
        bfrag[q] = *reinterpret_cast<const short*>(&h);
    }
    const float rb = bo[e] - r2[i * EOUT + e];

    const f32x4 zero = {0.f, 0.f, 0.f, 0.f};
    float* __restrict__ op = out + (size_t)i * LSEQ * EOUT;
    const short* __restrict__ lbf = reinterpret_cast<const short*>(left_bf);

    #pragma unroll 2
    for (int jt = 0; jt < LSEQ / 16; ++jt) {
        const bf16x8 afr = *reinterpret_cast<const bf16x8*>(lbf + (jt * 16 + n) * DOUT + 8 * g);
        const f32x4 dfr = __builtin_amdgcn_mfma_f32_16x16x32_bf16(afr, bfrag, zero, 0, 0, 0);
        const int j = jt * 16 + 4 * g;
        #pragma unroll
        for (int q = 0; q < 4; ++q) {
            op[(size_t)(j + q) * EOUT + e] = dfr[q] + l2[(j + q) * EOUT + e] + rb;
        }
    }
}

extern "C" void kernel_launch(void* const* d_in, const int* in_sizes, int n_in,
                              void* d_out, int out_size, void* d_ws, size_t ws_size,
                              hipStream_t stream) {
    const float* act  = (const float*)d_in[0];
    const float* mask = (const float*)d_in[1];
    const float* nw   = (const float*)d_in[2];
    const float* nb   = (const float*)d_in[3];
    const float* wl   = (const float*)d_in[4];
    const float* bl   = (const float*)d_in[5];
    const float* wr   = (const float*)d_in[6];
    const float* br   = (const float*)d_in[7];
    const float* wo   = (const float*)d_in[8];
    const float* bo   = (const float*)d_in[9];
    float* out = (float*)d_out;

    char* ws = (char*)d_ws;
    __hip_bfloat16* left_bf = (__hip_bfloat16*)(ws);            // 768*32*2  = 49152 B
    float* right = (float*)(ws + 49152);                        // 768*32*4  = 98304 B
    float* l2    = (float*)(ws + 49152 + 98304);                // 768*128*4 = 393216 B
    float* r2    = (float*)(ws + 49152 + 98304 + 393216);       // 768*128*4 = 393216 B

    hipLaunchKernelGGL(k_ln_proj, dim3(LSEQ), dim3(384), 0, stream,
                       act, mask, nw, nb, wl, bl, wr, br, wo,
                       left_bf, right, l2, r2);
    hipLaunchKernelGGL(k_outer_mfma, dim3(LSEQ), dim3(512), 0, stream,
                       left_bf, right, l2, r2, wo, bo, out);
}